// Round 8
// baseline (157.041 us; speedup 1.0000x reference)
//
#include <hip/hip_runtime.h>

// ---------------- problem constants (fixed by setup_inputs) ----------------
constexpr int B_ = 2, N_ = 8192, M_ = 8192, Dd = 64;
constexpr int TN = 128;              // n-rows per block (4 waves x 32, n-partitioned)
constexpr int TM = 64;               // ref rows per chunk
constexpr int SPLIT = 8;             // M-splits; blockIdx&7 pins split->XCD
constexpr int MCHUNK = M_ / SPLIT;   // 1024
constexpr int NCHUNKS = MCHUNK / TM; // 16
constexpr int NT = N_ / TN;          // 64
constexpr float LOG2E   = 1.4426950408889634f;
constexpr float SCALE_S = LOG2E / 64.0f;    //  dot/64    in log2 domain
constexpr float SCALE_N = -LOG2E / 128.0f;  // -|v|^2/128 in log2 domain

using s16x8 = __attribute__((ext_vector_type(8))) short;
using f32x4 = __attribute__((ext_vector_type(4))) float;
using f32x2v = __attribute__((ext_vector_type(2))) float;
using bf16x2 = __attribute__((ext_vector_type(2))) __bf16;

#if defined(__has_builtin)
#if __has_builtin(__builtin_amdgcn_exp2f)
#define EXP2(x) __builtin_amdgcn_exp2f(x)
#endif
#endif
#ifndef EXP2
#define EXP2(x) exp2f(x)
#endif

// f32 pair -> packed bf16 (RNE) via 2-wide vector fptrunc -> v_cvt_pk_bf16_f32.
__device__ __forceinline__ unsigned pk2(float lo, float hi) {
  f32x2v f;
  f[0] = lo;
  f[1] = hi;
  bf16x2 h = __builtin_convertvector(f, bf16x2);
  return __builtin_bit_cast(unsigned, h);
}
__device__ __forceinline__ f32x4 mfma16(s16x8 a, s16x8 b, f32x4 c) {
  return __builtin_amdgcn_mfma_f32_16x16x32_bf16(a, b, c, 0, 0, 0);
}
__device__ __forceinline__ float dot4(float4 f) {
  return f.x * f.x + f.y * f.y + f.z * f.z + f.w * f.w;
}

// Frag layouts (m89/m91): A/B: outer=lane&15, 8 k-contig at (lane>>4)*8.
// C/D: col = lane&15, row = (lane>>4)*4 + reg.
// Structure = R7 single-barrier double-buffer (stage c+1 overlapped with compute c),
// with LDS cut to 39,424 B so 4 blocks/CU fit (grid 1024 = exactly one generation,
// no tail -- R7's 52 KB / 3 blocks/CU left 256 blocks running at 1/3 occupancy).
//
// P scratch shrunk 16KB -> 4KB: PV split into ks-halves; ONE [16][32] quarter per
// wave is ping-pong reused (write rt=0, read pf0, overwrite rt=1, read pf1 -- all
// same-wave LDS, program-ordered, no barrier). LDS op count unchanged.
// Quarter swizzle: 16B chunk ch = (m>>3) ^ (l15&3)  (bijective per row; write b64
// conflict-free, read b128 balanced 8 lanes/chunk).
//
// ldsYT swizzle (R4-proven): (d,m) at 16B chunk F=((m>>3)+2*(d>>4)+(d&7))&7, off m&7.

__global__ __launch_bounds__(256, 4) void msflash_kernel(
    const float* __restrict__ pts, const float* __restrict__ ref,
    float* __restrict__ num_acc, float* __restrict__ den_acc) {
  __shared__ unsigned short ldsY2[2][TM][72];   // Y dbuf [m][d]; X/O alias    18432 B
  __shared__ unsigned short ldsYT2[2][Dd][64];  // Y^T dbuf [d][m] swizzled    16384 B
  __shared__ unsigned short ldsQ[4][16][32];    // per-wave P quarter (pingpong) 4096 B
  __shared__ float lds_bm2[2][TM];              // Y row norms dbuf              512 B
  // total 39,424 B -> 4 blocks/CU. X row norms alias into ldsQ (prologue only).

  const int tid  = threadIdx.x;
  const int w    = tid >> 6;
  const int lane = tid & 63;
  const int l15  = lane & 15, quad = lane >> 4;
  const int ytsw = quad + (l15 & 7);            // YT read F-base
  const int psm  = l15 & 3;                     // quarter-P swizzle mask

  const int s  = blockIdx.x & (SPLIT - 1);
  const int r  = blockIdx.x >> 3;
  const int bb = r / NT;
  const int nt_ = r % NT;
  const int n0 = nt_ * TN;
  const int m_begin = s * MCHUNK;

  // ---- staging thread mapping (Y): 64 rows x 4 threads x 16 d each ----
  const int rowl_s = tid >> 2, q_s = tid & 3;
  const float* ybase = ref + ((size_t)bb * M_ + m_begin + rowl_s) * Dd + q_s * 16;
  float4 fv0, fv1, fv2, fv3;

  auto loadfv = [&](int cc) {
    const float* yp = ybase + (size_t)cc * TM * Dd;
    fv0 = ((const float4*)yp)[0];
    fv1 = ((const float4*)yp)[1];
    fv2 = ((const float4*)yp)[2];
    fv3 = ((const float4*)yp)[3];
  };
  auto stage = [&](int bp) {   // convert fv -> ldsY2[bp], ldsYT2[bp], lds_bm2[bp]
    unsigned pkd[8] = {pk2(fv0.x, fv0.y), pk2(fv0.z, fv0.w),
                       pk2(fv1.x, fv1.y), pk2(fv1.z, fv1.w),
                       pk2(fv2.x, fv2.y), pk2(fv2.z, fv2.w),
                       pk2(fv3.x, fv3.y), pk2(fv3.z, fv3.w)};
    float sq = dot4(fv0) + dot4(fv1) + dot4(fv2) + dot4(fv3);
    sq += __shfl_xor(sq, 1);
    sq += __shfl_xor(sq, 2);
    if (q_s == 0) lds_bm2[bp][rowl_s] = sq * SCALE_N;
    uint4* dv = (uint4*)&ldsY2[bp][rowl_s][q_s * 16];
    dv[0] = make_uint4(pkd[0], pkd[1], pkd[2], pkd[3]);
    dv[1] = make_uint4(pkd[4], pkd[5], pkd[6], pkd[7]);
    const int tsw = (rowl_s >> 3) + 2 * q_s;
    const int mlo = rowl_s & 7;
#pragma unroll
    for (int j = 0; j < 8; j++) {
      const int d0 = q_s * 16 + 2 * j;
      const int c0 = (tsw + ((2 * j) & 7)) & 7;
      const int c1 = (tsw + ((2 * j + 1) & 7)) & 7;
      ldsYT2[bp][d0][(c0 << 3) + mlo]     = (unsigned short)pkd[j];
      ldsYT2[bp][d0 + 1][(c1 << 3) + mlo] = (unsigned short)(pkd[j] >> 16);
    }
  };

  // ---- prologue: X stage into Y-dbuf alias + chunk-0 stage into buf 0 ----
  loadfv(0);
  unsigned short (*ldsX)[72] = (unsigned short (*)[72]) & ldsY2[0][0][0];  // [128][72]
  float* lds_an2 = (float*)&ldsQ[0][0][0];  // 512 B alias, prologue-only
  {
    const int rowl = tid >> 1, half = tid & 1;
    const float* gp = pts + ((size_t)bb * N_ + n0 + rowl) * Dd + half * 32;
    float sq = 0.f;
    unsigned pkd[16];
#pragma unroll
    for (int i = 0; i < 8; i++) {
      float4 f = ((const float4*)gp)[i];
      sq += dot4(f);
      pkd[2 * i + 0] = pk2(f.x, f.y);
      pkd[2 * i + 1] = pk2(f.z, f.w);
    }
    sq += __shfl_xor(sq, 1);
    if (half == 0) lds_an2[rowl] = sq * SCALE_N;
    uint4* dv = (uint4*)&ldsX[rowl][half * 32];
#pragma unroll
    for (int i = 0; i < 4; i++)
      dv[i] = make_uint4(pkd[4 * i], pkd[4 * i + 1], pkd[4 * i + 2], pkd[4 * i + 3]);
  }
  __syncthreads();

  // X B-frags (col = n) + per-row -|x|^2 term -> registers
  s16x8 bx[2][2];
  float anr_s[2];
#pragma unroll
  for (int rt = 0; rt < 2; rt++) {
#pragma unroll
    for (int ks = 0; ks < 2; ks++)
      bx[rt][ks] = *(const s16x8*)&ldsX[w * 32 + rt * 16 + l15][ks * 32 + quad * 8];
    anr_s[rt] = lds_an2[w * 32 + rt * 16 + l15];
  }
  __syncthreads();   // all bx/anr reads done before chunk-0 writes overwrite aliases

  stage(0);
  loadfv(1);
  __syncthreads();   // buf 0 visible

  f32x4 o[2][4], den[2];
#pragma unroll
  for (int rt = 0; rt < 2; rt++) {
    den[rt] = f32x4{0.f, 0.f, 0.f, 0.f};
#pragma unroll
    for (int dt = 0; dt < 4; dt++) o[rt][dt] = f32x4{0.f, 0.f, 0.f, 0.f};
  }
  s16x8 ones;  // A row 0 all-ones -> D row 0 = column sums of B
#pragma unroll
  for (int j = 0; j < 8; j++) ones[j] = (l15 == 0) ? (short)0x3F80 : (short)0;

  int p = 0;
  for (int c = 0; c < NCHUNKS; ++c) {
    // ================= COMPUTE chunk c from buf p =================
    // QK: S^T tiles, A = Y[m][d] from ldsY2[p], B = bx (regs)
    f32x4 sf[2][4];
#pragma unroll
    for (int ct = 0; ct < 4; ct++) {
      s16x8 a0 = *(const s16x8*)&ldsY2[p][ct * 16 + l15][quad * 8];
      s16x8 a1 = *(const s16x8*)&ldsY2[p][ct * 16 + l15][32 + quad * 8];
#pragma unroll
      for (int rt = 0; rt < 2; rt++) {
        f32x4 acc = f32x4{0.f, 0.f, 0.f, 0.f};
        acc = mfma16(a0, bx[rt][0], acc);
        acc = mfma16(a1, bx[rt][1], acc);
        sf[rt][ct] = acc;
      }
    }
    // ---- per ks-half: exp2 -> quarter-P pingpong -> PV ----
#pragma unroll
    for (int ks = 0; ks < 2; ks++) {
      f32x4 bmA = *(const f32x4*)&lds_bm2[p][(2 * ks + 0) * 16 + quad * 4];
      f32x4 bmB = *(const f32x4*)&lds_bm2[p][(2 * ks + 1) * 16 + quad * 4];
      s16x8 pf01[2];
#pragma unroll
      for (int rt = 0; rt < 2; rt++) {
#pragma unroll
        for (int cl = 0; cl < 2; cl++) {
          const f32x4& bm = cl ? bmB : bmA;
          const f32x4& sv = sf[rt][2 * ks + cl];
          float e0 = EXP2(sv[0] * SCALE_S + (anr_s[rt] + bm[0]));
          float e1 = EXP2(sv[1] * SCALE_S + (anr_s[rt] + bm[1]));
          float e2 = EXP2(sv[2] * SCALE_S + (anr_s[rt] + bm[2]));
          float e3 = EXP2(sv[3] * SCALE_S + (anr_s[rt] + bm[3]));
          // m_local = cl*16 + quad*4 -> chunk (2cl + (quad>>1)) ^ psm, half (quad&1)
          const int ch = ((2 * cl + (quad >> 1)) ^ psm);
          *(uint2*)&ldsQ[w][l15][ch * 8 + (quad & 1) * 4] =
              make_uint2(pk2(e0, e1), pk2(e2, e3));
        }
        // read back this rt's frag (m_local = quad*8.. -> chunk quad ^ psm)
        pf01[rt] = *(const s16x8*)&ldsQ[w][l15][(quad ^ psm) * 8];
      }
#pragma unroll
      for (int dt = 0; dt < 4; dt++) {
        const unsigned short* yt = &ldsYT2[p][dt * 16 + l15][0];
        s16x8 a = *(const s16x8*)&yt[((ytsw + 4 * ks + 2 * dt) & 7) << 3];
        o[0][dt] = mfma16(a, pf01[0], o[0][dt]);
        o[1][dt] = mfma16(a, pf01[1], o[1][dt]);
      }
      den[0] = mfma16(ones, pf01[0], den[0]);
      den[1] = mfma16(ones, pf01[1], den[1]);
    }
    // ================= STAGE chunk c+1 into buf p^1 (overlapped) =================
    // Branchless: at c = NCHUNKS-1 this restages chunk 15 into the dead buffer.
    stage(p ^ 1);
    loadfv(c + 2 < NCHUNKS ? c + 2 : NCHUNKS - 1);
    __syncthreads();
    p ^= 1;
  }

  // ---- epilogue: transpose O^T via wave-private scratch over the Y-dbuf alias ----
  // o[rt][dt][g] = O[n = w*32+rt*16+l15][d = dt*16+quad*4+g]
  float* ldsO = (float*)&ldsY2[0][0][0] + (size_t)w * 1152;  // 32 rows * 36 floats/wave
  float* nb = num_acc + ((size_t)bb * N_ + n0) * Dd;
#pragma unroll
  for (int rt = 0; rt < 2; rt++) {
#pragma unroll
    for (int dt = 0; dt < 4; dt++) {
      const int base = l15 * 66 + dt * 16 + quad * 4;
      *(float2*)&ldsO[base + 0] = make_float2(o[rt][dt][0], o[rt][dt][1]);
      *(float2*)&ldsO[base + 2] = make_float2(o[rt][dt][2], o[rt][dt][3]);
    }
    const int nrow = w * 32 + rt * 16;  // wave-private region: in-order LDS, no barrier
#pragma unroll
    for (int rr = 0; rr < 16; rr++) {
      float v = ldsO[rr * 66 + lane];
      atomicAdd(&nb[(size_t)(nrow + rr) * Dd + lane], v);  // 256B contiguous per instr
    }
    if (quad == 0)
      atomicAdd(&den_acc[(size_t)bb * N_ + n0 + nrow + l15], den[rt][0]);
  }
}

__global__ __launch_bounds__(256) void msdiv_kernel(
    const float* __restrict__ num, const float* __restrict__ den,
    float* __restrict__ out) {
  const int i = blockIdx.x * 256 + threadIdx.x;  // float4 index; grid covers exactly
  float4 v = ((const float4*)num)[i];
  const float inv = 1.0f / den[i >> 4];          // 16 float4 per 64-wide row
  ((float4*)out)[i] = make_float4(v.x * inv, v.y * inv, v.z * inv, v.w * inv);
}

extern "C" void kernel_launch(void* const* d_in, const int* in_sizes, int n_in,
                              void* d_out, int out_size, void* d_ws, size_t ws_size,
                              hipStream_t stream) {
  const float* pts = (const float*)d_in[0];
  const float* ref = (const float*)d_in[1];
  float* out = (float*)d_out;
  float* num = (float*)d_ws;                       // [B,N,64] fp32 partial numerators
  float* den = num + (size_t)B_ * N_ * Dd;         // [B,N]    fp32 partial denominators
  const size_t acc_bytes = ((size_t)B_ * N_ * Dd + (size_t)B_ * N_) * sizeof(float);

  hipMemsetAsync(d_ws, 0, acc_bytes, stream);      // ws is re-poisoned 0xAA each launch
  msflash_kernel<<<dim3(B_ * NT * SPLIT), dim3(256), 0, stream>>>(pts, ref, num, den);
  const int tot4 = B_ * N_ * Dd / 4;               // 262144
  msdiv_kernel<<<dim3(tot4 / 256), dim3(256), 0, stream>>>(num, den, out);
}

// Round 9
// 129.121 us; speedup vs baseline: 1.2162x; 1.2162x over previous
//
#include <hip/hip_runtime.h>

// ---------------- problem constants (fixed by setup_inputs) ----------------
constexpr int B_ = 2, N_ = 8192, M_ = 8192, Dd = 64;
constexpr int TN = 128;              // n-rows per block (4 waves x 32 n each)
constexpr int TM = 64;               // ref rows per chunk
constexpr int SPLIT = 8;             // M-splits; blockIdx&7 pins split->XCD
constexpr int MCHUNK = M_ / SPLIT;   // 1024
constexpr int NCHUNKS = MCHUNK / TM; // 16
constexpr int NT = N_ / TN;          // 64
constexpr float LOG2E   = 1.4426950408889634f;
constexpr float SCALE_S = LOG2E / 64.0f;    //  dot/64    in log2 domain
constexpr float SCALE_N = -LOG2E / 128.0f;  // -|v|^2/128 in log2 domain

using s16x8  = __attribute__((ext_vector_type(8))) short;
using f32x16 = __attribute__((ext_vector_type(16))) float;
using f32x2v = __attribute__((ext_vector_type(2))) float;
using bf16x2 = __attribute__((ext_vector_type(2))) __bf16;

#if defined(__has_builtin)
#if __has_builtin(__builtin_amdgcn_exp2f)
#define EXP2(x) __builtin_amdgcn_exp2f(x)
#endif
#endif
#ifndef EXP2
#define EXP2(x) exp2f(x)
#endif

// f32 pair -> packed bf16 (RNE) via 2-wide vector fptrunc -> v_cvt_pk_bf16_f32.
__device__ __forceinline__ unsigned pk2(float lo, float hi) {
  f32x2v f;
  f[0] = lo;
  f[1] = hi;
  bf16x2 h = __builtin_convertvector(f, bf16x2);
  return __builtin_bit_cast(unsigned, h);
}
__device__ __forceinline__ f32x16 mfma32(s16x8 a, s16x8 b, f32x16 c) {
  return __builtin_amdgcn_mfma_f32_32x32x16_bf16(a, b, c, 0, 0, 0);
}
__device__ __forceinline__ float dot4(float4 f) {
  return f.x * f.x + f.y * f.y + f.z * f.z + f.w * f.w;
}

// 32x32x16 layouts: A: row=lane&31, k=(lane>>5)*8+elem. B: col=lane&31, k same.
// C/D (m74/m101-verified): col=lane&31, row=(reg&3)+8*(reg>>2)+4*(lane>>5).
//
// P path (NO LDS): QK C gives lane (n=c32, hi) rows m_local={(r&3)+8(r>>2)+4hi}.
// PV B-frag kstep kk needs m=kk*16+hi*8+[0,8). pack pairs dw[j] (m-pair base
// 8*(j>>1)+4hi+2*(j&1)), swap all 8 via shfl_xor(.,32); frag dwords:
//   f0=hi?sw[4kk+2]:dw[4kk], f1=hi?sw[4kk+3]:dw[4kk+1],
//   f2=hi?dw[4kk+2]:sw[4kk], f3=hi?dw[4kk+3]:sw[4kk+1].
// den = lane-sum of own exps (+1 final swap-add) - ones-MFMA eliminated.
//
// ldsYT swizzle (R4-proven): (d,m) at 16B chunk F=((m>>3)+2*(d>>4)+(d&7))&7, off m&7.
// Read (d=dtile*32+c32, m-octet 2ks+hi): F=(2ks+hi+4dtile+2*(c32>>4)+(c32&7))&7.

__global__ __launch_bounds__(256, 4) void msflash_kernel(
    const float* __restrict__ pts, const float* __restrict__ ref,
    float* __restrict__ num_acc, float* __restrict__ den_acc) {
  // one 18,944 B pool (4 blocks/CU now reg-limited, not LDS-limited):
  //  [0,9216):      ldsY [64][72]   (QK A)   | prologue: X-stage [128][72] spans [0,18432)
  //  [9216,17408):  ldsYT [64][64]  (PV A, swizzled)
  //  [17408,17664): bm2 [64] f32    (chunk Y norms; overlaps X rows 120-122, written post-prologue)
  //  [18432,18944): an2 [128] f32   (X norms, prologue only)
  //  epilogue: scratch [0,18432) = 4 waves x [32][36] f32
  __shared__ __align__(16) unsigned char smem[18944];
  unsigned short (*ldsY)[72]  = (unsigned short (*)[72])  smem;
  unsigned short (*ldsYT)[64] = (unsigned short (*)[64]) (smem + 9216);
  float* bm2 = (float*)(smem + 17408);
  float* an2 = (float*)(smem + 18432);

  const int tid  = threadIdx.x;
  const int w    = tid >> 6;
  const int lane = tid & 63;
  const int c32  = lane & 31;
  const int hi   = lane >> 5;

  const int s  = blockIdx.x & (SPLIT - 1);
  const int r  = blockIdx.x >> 3;
  const int bb = r / NT;
  const int nt_ = r % NT;
  const int n0 = nt_ * TN;
  const int m_begin = s * MCHUNK;

  // ---- staging thread mapping (Y): 64 rows x 4 threads x 16 d each ----
  const int rowl_s = tid >> 2, q_s = tid & 3;
  const float* ybase = ref + ((size_t)bb * M_ + m_begin + rowl_s) * Dd + q_s * 16;

  auto stage = [&](int cc) {   // load+convert chunk cc -> ldsY, ldsYT, bm2
    const float* yp = ybase + (size_t)cc * TM * Dd;
    float4 a0 = ((const float4*)yp)[0];
    float4 a1 = ((const float4*)yp)[1];
    float4 a2 = ((const float4*)yp)[2];
    float4 a3 = ((const float4*)yp)[3];
    unsigned pkd[8] = {pk2(a0.x, a0.y), pk2(a0.z, a0.w), pk2(a1.x, a1.y), pk2(a1.z, a1.w),
                       pk2(a2.x, a2.y), pk2(a2.z, a2.w), pk2(a3.x, a3.y), pk2(a3.z, a3.w)};
    float sq = dot4(a0) + dot4(a1) + dot4(a2) + dot4(a3);
    sq += __shfl_xor(sq, 1);
    sq += __shfl_xor(sq, 2);
    if (q_s == 0) bm2[rowl_s] = sq * SCALE_N;
    uint4* dv = (uint4*)&ldsY[rowl_s][q_s * 16];
    dv[0] = make_uint4(pkd[0], pkd[1], pkd[2], pkd[3]);
    dv[1] = make_uint4(pkd[4], pkd[5], pkd[6], pkd[7]);
    const int tsw = (rowl_s >> 3) + 2 * q_s;
    const int mlo = rowl_s & 7;
#pragma unroll
    for (int j = 0; j < 8; j++) {
      const int d0 = q_s * 16 + 2 * j;
      const int c0 = (tsw + ((2 * j) & 7)) & 7;
      const int c1 = (tsw + ((2 * j + 1) & 7)) & 7;
      ldsYT[d0][(c0 << 3) + mlo]     = (unsigned short)pkd[j];
      ldsYT[d0 + 1][(c1 << 3) + mlo] = (unsigned short)(pkd[j] >> 16);
    }
  };

  // ---- prologue: X stage (fp32->bf16) into pool [128][72] + row norms ----
  unsigned short (*ldsX)[72] = (unsigned short (*)[72]) smem;
  {
    const int rowl = tid >> 1, half = tid & 1;
    const float* gp = pts + ((size_t)bb * N_ + n0 + rowl) * Dd + half * 32;
    float sq = 0.f;
    unsigned pkd[16];
#pragma unroll
    for (int i = 0; i < 8; i++) {
      float4 f = ((const float4*)gp)[i];
      sq += dot4(f);
      pkd[2 * i + 0] = pk2(f.x, f.y);
      pkd[2 * i + 1] = pk2(f.z, f.w);
    }
    sq += __shfl_xor(sq, 1);
    if (half == 0) an2[rowl] = sq * SCALE_N;
    uint4* dv = (uint4*)&ldsX[rowl][half * 32];
#pragma unroll
    for (int i = 0; i < 4; i++)
      dv[i] = make_uint4(pkd[4 * i], pkd[4 * i + 1], pkd[4 * i + 2], pkd[4 * i + 3]);
  }
  __syncthreads();

  // X B-frags (col n = w*32+c32) + -|x|^2 term -> registers
  s16x8 bx[4];
#pragma unroll
  for (int k = 0; k < 4; k++)
    bx[k] = *(const s16x8*)&ldsX[w * 32 + c32][k * 16 + hi * 8];
  const float anr = an2[w * 32 + c32];

  f32x16 o0, o1;
#pragma unroll
  for (int i = 0; i < 16; i++) { o0[i] = 0.f; o1[i] = 0.f; }
  float dacc = 0.f;

  const int ytbase = hi + 2 * (c32 >> 4) + (c32 & 7);  // thread-const part of YT read F

  for (int c = 0; c < NCHUNKS; ++c) {
    __syncthreads();   // previous chunk's reads (and prologue bx reads) done
    stage(c);
    __syncthreads();   // chunk staged

#pragma unroll
    for (int t = 0; t < 2; t++) {
      // QK: S^T 32x32 tile (A = Y rows t*32+c32, B = bx)
      f32x16 sf;
#pragma unroll
      for (int i = 0; i < 16; i++) sf[i] = 0.f;
#pragma unroll
      for (int k = 0; k < 4; k++) {
        s16x8 a = *(const s16x8*)&ldsY[t * 32 + c32][k * 16 + hi * 8];
        sf = mfma32(a, bx[k], sf);
      }
      // exp2 + pack (C row m = t*32 + (reg&3)+8*(reg>>2)+4*hi)
      unsigned dw[8], sw[8];
#pragma unroll
      for (int rg = 0; rg < 4; rg++) {
        float4 bm = *(const float4*)&bm2[t * 32 + 8 * rg + 4 * hi];
        float e0 = EXP2(sf[4 * rg + 0] * SCALE_S + (anr + bm.x));
        float e1 = EXP2(sf[4 * rg + 1] * SCALE_S + (anr + bm.y));
        float e2 = EXP2(sf[4 * rg + 2] * SCALE_S + (anr + bm.z));
        float e3 = EXP2(sf[4 * rg + 3] * SCALE_S + (anr + bm.w));
        dacc += (e0 + e1) + (e2 + e3);
        dw[2 * rg + 0] = pk2(e0, e1);
        dw[2 * rg + 1] = pk2(e2, e3);
      }
#pragma unroll
      for (int j = 0; j < 8; j++) sw[j] = __shfl_xor(dw[j], 32);
      // PV: per local kstep build P-frag in-reg, accumulate both d-tiles
#pragma unroll
      for (int kk = 0; kk < 2; kk++) {
        unsigned f0 = hi ? sw[4 * kk + 2] : dw[4 * kk + 0];
        unsigned f1 = hi ? sw[4 * kk + 3] : dw[4 * kk + 1];
        unsigned f2 = hi ? dw[4 * kk + 2] : sw[4 * kk + 0];
        unsigned f3 = hi ? dw[4 * kk + 3] : sw[4 * kk + 1];
        s16x8 pf = __builtin_bit_cast(s16x8, make_uint4(f0, f1, f2, f3));
        const int ks = 2 * t + kk;
        const int F0 = (2 * ks + ytbase) & 7;        // dtile 0
        const int F1 = (2 * ks + ytbase + 4) & 7;    // dtile 1 (4*dtile)
        s16x8 a0 = *(const s16x8*)&ldsYT[c32][F0 * 8];
        s16x8 a1 = *(const s16x8*)&ldsYT[32 + c32][F1 * 8];
        o0 = mfma32(a0, pf, o0);
        o1 = mfma32(a1, pf, o1);
      }
    }
  }

  // ---- epilogue ----
  dacc += __shfl_xor(dacc, 32);   // full den[n=c32] in every lane
  __syncthreads();                // all waves done reading ldsY/ldsYT
  // O^T -> O transpose via wave-private scratch [32 n][36 d-pad] (stride 144B, b128-aligned)
  float* sc = (float*)smem + (size_t)w * 1152;   // 4608 B per wave
  float* nb = num_acc + ((size_t)bb * N_ + n0 + w * 32) * Dd;
#pragma unroll
  for (int h = 0; h < 2; h++) {                  // d-tile halves
    const f32x16& oh = h ? o1 : o0;
#pragma unroll
    for (int rg = 0; rg < 4; rg++) {
      // d_local = 8*rg + 4*hi + g, n = c32
      *(float4*)&sc[c32 * 36 + 8 * rg + 4 * hi] =
          make_float4(oh[4 * rg + 0], oh[4 * rg + 1], oh[4 * rg + 2], oh[4 * rg + 3]);
    }
    // wave-private in-order LDS: read rows, coalesced atomics (2 n-rows x 32 d per instr)
#pragma unroll
    for (int rr = 0; rr < 16; rr++) {
      const int row = 2 * rr + hi;
      float v = sc[row * 36 + c32];
      atomicAdd(&nb[(size_t)row * Dd + h * 32 + c32], v);
    }
  }
  if (hi == 0)
    atomicAdd(&den_acc[(size_t)bb * N_ + n0 + w * 32 + c32], dacc);
}

__global__ __launch_bounds__(256) void msdiv_kernel(
    const float* __restrict__ num, const float* __restrict__ den,
    float* __restrict__ out) {
  const int i = blockIdx.x * 256 + threadIdx.x;  // float4 index; grid covers exactly
  float4 v = ((const float4*)num)[i];
  const float inv = 1.0f / den[i >> 4];          // 16 float4 per 64-wide row
  ((float4*)out)[i] = make_float4(v.x * inv, v.y * inv, v.z * inv, v.w * inv);
}

extern "C" void kernel_launch(void* const* d_in, const int* in_sizes, int n_in,
                              void* d_out, int out_size, void* d_ws, size_t ws_size,
                              hipStream_t stream) {
  const float* pts = (const float*)d_in[0];
  const float* ref = (const float*)d_in[1];
  float* out = (float*)d_out;
  float* num = (float*)d_ws;                       // [B,N,64] fp32 partial numerators
  float* den = num + (size_t)B_ * N_ * Dd;         // [B,N]    fp32 partial denominators
  const size_t acc_bytes = ((size_t)B_ * N_ * Dd + (size_t)B_ * N_) * sizeof(float);

  hipMemsetAsync(d_ws, 0, acc_bytes, stream);      // ws is re-poisoned 0xAA each launch
  msflash_kernel<<<dim3(B_ * NT * SPLIT), dim3(256), 0, stream>>>(pts, ref, num, den);
  const int tot4 = B_ * N_ * Dd / 4;               // 262144
  msdiv_kernel<<<dim3(tot4 / 256), dim3(256), 0, stream>>>(num, den, out);
}

// Round 10
// 128.393 us; speedup vs baseline: 1.2231x; 1.0057x over previous
//
#include <hip/hip_runtime.h>

// ---------------- problem constants (fixed by setup_inputs) ----------------
constexpr int B_ = 2, N_ = 8192, M_ = 8192, Dd = 64;
constexpr int TN = 128;              // n-rows per block (4 waves x 32 n each)
constexpr int TM = 64;               // ref rows per SUB-chunk
constexpr int SPLIT = 8;             // M-splits; blockIdx&7 pins split->XCD
constexpr int MCHUNK = M_ / SPLIT;   // 1024
constexpr int NCHUNKS = MCHUNK / (2 * TM); // 8 outer chunks of 128 rows
constexpr int NT = N_ / TN;          // 64
constexpr float LOG2E   = 1.4426950408889634f;
constexpr float SCALE_S = LOG2E / 64.0f;    //  dot/64    in log2 domain
constexpr float SCALE_N = -LOG2E / 128.0f;  // -|v|^2/128 in log2 domain

using s16x8  = __attribute__((ext_vector_type(8))) short;
using f32x16 = __attribute__((ext_vector_type(16))) float;
using f32x2v = __attribute__((ext_vector_type(2))) float;
using bf16x2 = __attribute__((ext_vector_type(2))) __bf16;

#if defined(__has_builtin)
#if __has_builtin(__builtin_amdgcn_exp2f)
#define EXP2(x) __builtin_amdgcn_exp2f(x)
#endif
#endif
#ifndef EXP2
#define EXP2(x) exp2f(x)
#endif

// f32 pair -> packed bf16 (RNE) via 2-wide vector fptrunc -> v_cvt_pk_bf16_f32.
__device__ __forceinline__ unsigned pk2(float lo, float hi) {
  f32x2v f;
  f[0] = lo;
  f[1] = hi;
  bf16x2 h = __builtin_convertvector(f, bf16x2);
  return __builtin_bit_cast(unsigned, h);
}
__device__ __forceinline__ f32x16 mfma32(s16x8 a, s16x8 b, f32x16 c) {
  return __builtin_amdgcn_mfma_f32_32x32x16_bf16(a, b, c, 0, 0, 0);
}
__device__ __forceinline__ float dot4(float4 f) {
  return f.x * f.x + f.y * f.y + f.z * f.z + f.w * f.w;
}

// 32x32x16 layouts: A: row=lane&31, k=(lane>>5)*8+elem. B: col=lane&31, k same.
// C/D (m74/m101-verified): col=lane&31, row=(reg&3)+8*(reg>>2)+4*(lane>>5).
// P path (NO LDS), shfl_xor(.,32) redistribution, den lane-local: R9-proven.
// ldsYT swizzle (R4-proven): (d,m) at 16B chunk F=((m>>3)+2*(d>>4)+(d&7))&7, off m&7.
//
// THIS ROUND (latency-bound fix): outer chunk = 128 rows = TWO R9 sub-chunks staged
// into [2]-indexed buffers behind ONE barrier pair. The compute body then holds
// FOUR independent QK->exp->shfl->PV streams (2 sub x 2 tiles) for the scheduler
// to braid (R9 had 2); barriers halve 32 -> 16. All pieces carried verbatim.

__global__ __launch_bounds__(256, 4) void msflash_kernel(
    const float* __restrict__ pts, const float* __restrict__ ref,
    float* __restrict__ num_acc, float* __restrict__ den_acc) {
  __shared__ unsigned short ldsY[2][TM][72];   // QK A dbuf-by-sub; X-stage [128][72] alias; O-scratch
  __shared__ unsigned short ldsYT[2][Dd][64];  // PV A (swizzled), per sub
  __shared__ float bm2[2][TM];                 // Y row norms per sub
  __shared__ float an2[TN];                    // X row norms (prologue only)
  // total 35,840 B -> 4 blocks/CU

  const int tid  = threadIdx.x;
  const int w    = tid >> 6;
  const int lane = tid & 63;
  const int c32  = lane & 31;
  const int hi   = lane >> 5;

  const int s  = blockIdx.x & (SPLIT - 1);
  const int r  = blockIdx.x >> 3;
  const int bb = r / NT;
  const int nt_ = r % NT;
  const int n0 = nt_ * TN;
  const int m_begin = s * MCHUNK;

  // ---- staging thread mapping (Y): 64 rows x 4 threads x 16 d each ----
  const int rowl_s = tid >> 2, q_s = tid & 3;
  const float* ybase = ref + ((size_t)bb * M_ + m_begin + rowl_s) * Dd + q_s * 16;

  auto stage = [&](int sub, int sc) {  // load+convert 64-row sub-chunk sc -> slot sub
    const float* yp = ybase + (size_t)sc * TM * Dd;
    float4 a0 = ((const float4*)yp)[0];
    float4 a1 = ((const float4*)yp)[1];
    float4 a2 = ((const float4*)yp)[2];
    float4 a3 = ((const float4*)yp)[3];
    unsigned pkd[8] = {pk2(a0.x, a0.y), pk2(a0.z, a0.w), pk2(a1.x, a1.y), pk2(a1.z, a1.w),
                       pk2(a2.x, a2.y), pk2(a2.z, a2.w), pk2(a3.x, a3.y), pk2(a3.z, a3.w)};
    float sq = dot4(a0) + dot4(a1) + dot4(a2) + dot4(a3);
    sq += __shfl_xor(sq, 1);
    sq += __shfl_xor(sq, 2);
    if (q_s == 0) bm2[sub][rowl_s] = sq * SCALE_N;
    uint4* dv = (uint4*)&ldsY[sub][rowl_s][q_s * 16];
    dv[0] = make_uint4(pkd[0], pkd[1], pkd[2], pkd[3]);
    dv[1] = make_uint4(pkd[4], pkd[5], pkd[6], pkd[7]);
    const int tsw = (rowl_s >> 3) + 2 * q_s;
    const int mlo = rowl_s & 7;
#pragma unroll
    for (int j = 0; j < 8; j++) {
      const int d0 = q_s * 16 + 2 * j;
      const int c0 = (tsw + ((2 * j) & 7)) & 7;
      const int c1 = (tsw + ((2 * j + 1) & 7)) & 7;
      ldsYT[sub][d0][(c0 << 3) + mlo]     = (unsigned short)pkd[j];
      ldsYT[sub][d0 + 1][(c1 << 3) + mlo] = (unsigned short)(pkd[j] >> 16);
    }
  };

  // ---- prologue: X stage (fp32->bf16) into ldsY alias [128][72] + row norms ----
  unsigned short (*ldsX)[72] = (unsigned short (*)[72]) & ldsY[0][0][0];
  {
    const int rowl = tid >> 1, half = tid & 1;
    const float* gp = pts + ((size_t)bb * N_ + n0 + rowl) * Dd + half * 32;
    float sq = 0.f;
    unsigned pkd[16];
#pragma unroll
    for (int i = 0; i < 8; i++) {
      float4 f = ((const float4*)gp)[i];
      sq += dot4(f);
      pkd[2 * i + 0] = pk2(f.x, f.y);
      pkd[2 * i + 1] = pk2(f.z, f.w);
    }
    sq += __shfl_xor(sq, 1);
    if (half == 0) an2[rowl] = sq * SCALE_N;
    uint4* dv = (uint4*)&ldsX[rowl][half * 32];
#pragma unroll
    for (int i = 0; i < 4; i++)
      dv[i] = make_uint4(pkd[4 * i], pkd[4 * i + 1], pkd[4 * i + 2], pkd[4 * i + 3]);
  }
  __syncthreads();

  // X B-frags (col n = w*32+c32) + -|x|^2 term -> registers
  s16x8 bx[4];
#pragma unroll
  for (int k = 0; k < 4; k++)
    bx[k] = *(const s16x8*)&ldsX[w * 32 + c32][k * 16 + hi * 8];
  const float anr = an2[w * 32 + c32];

  f32x16 o0, o1;
#pragma unroll
  for (int i = 0; i < 16; i++) { o0[i] = 0.f; o1[i] = 0.f; }
  float dacc = 0.f;

  const int ytbase = hi + 2 * (c32 >> 4) + (c32 & 7);  // thread-const part of YT read F

  for (int c = 0; c < NCHUNKS; ++c) {
    __syncthreads();   // previous chunk's reads (and prologue bx reads) done
    stage(0, 2 * c);
    stage(1, 2 * c + 1);
    __syncthreads();   // both sub-chunks staged

#pragma unroll
    for (int sub = 0; sub < 2; sub++) {
#pragma unroll
      for (int t = 0; t < 2; t++) {
        // QK: S^T 32x32 tile (A = Y rows t*32+c32 of this sub, B = bx)
        f32x16 sf;
#pragma unroll
        for (int i = 0; i < 16; i++) sf[i] = 0.f;
#pragma unroll
        for (int k = 0; k < 4; k++) {
          s16x8 a = *(const s16x8*)&ldsY[sub][t * 32 + c32][k * 16 + hi * 8];
          sf = mfma32(a, bx[k], sf);
        }
        // exp2 + pack (C row m = t*32 + (reg&3)+8*(reg>>2)+4*hi)
        unsigned dw[8], sw[8];
#pragma unroll
        for (int rg = 0; rg < 4; rg++) {
          float4 bm = *(const float4*)&bm2[sub][t * 32 + 8 * rg + 4 * hi];
          float e0 = EXP2(sf[4 * rg + 0] * SCALE_S + (anr + bm.x));
          float e1 = EXP2(sf[4 * rg + 1] * SCALE_S + (anr + bm.y));
          float e2 = EXP2(sf[4 * rg + 2] * SCALE_S + (anr + bm.z));
          float e3 = EXP2(sf[4 * rg + 3] * SCALE_S + (anr + bm.w));
          dacc += (e0 + e1) + (e2 + e3);
          dw[2 * rg + 0] = pk2(e0, e1);
          dw[2 * rg + 1] = pk2(e2, e3);
        }
#pragma unroll
        for (int j = 0; j < 8; j++) sw[j] = __shfl_xor(dw[j], 32);
        // PV: per local kstep build P-frag in-reg, accumulate both d-tiles
#pragma unroll
        for (int kk = 0; kk < 2; kk++) {
          unsigned f0 = hi ? sw[4 * kk + 2] : dw[4 * kk + 0];
          unsigned f1 = hi ? sw[4 * kk + 3] : dw[4 * kk + 1];
          unsigned f2 = hi ? dw[4 * kk + 2] : sw[4 * kk + 0];
          unsigned f3 = hi ? dw[4 * kk + 3] : sw[4 * kk + 1];
          s16x8 pf = __builtin_bit_cast(s16x8, make_uint4(f0, f1, f2, f3));
          const int ks = 2 * t + kk;
          const int F0 = (2 * ks + ytbase) & 7;        // dtile 0
          const int F1 = (2 * ks + ytbase + 4) & 7;    // dtile 1 (4*dtile)
          s16x8 a0 = *(const s16x8*)&ldsYT[sub][c32][F0 * 8];
          s16x8 a1 = *(const s16x8*)&ldsYT[sub][32 + c32][F1 * 8];
          o0 = mfma32(a0, pf, o0);
          o1 = mfma32(a1, pf, o1);
        }
      }
    }
  }

  // ---- epilogue ----
  dacc += __shfl_xor(dacc, 32);   // full den[n=c32] in every lane
  __syncthreads();                // all waves done reading ldsY/ldsYT
  // O^T -> O transpose via wave-private scratch [32 n][36 d-pad] over ldsY alias
  float* sc = (float*)&ldsY[0][0][0] + (size_t)w * 1152;   // 4608 B per wave
  float* nb = num_acc + ((size_t)bb * N_ + n0 + w * 32) * Dd;
#pragma unroll
  for (int h = 0; h < 2; h++) {                  // d-tile halves
    const f32x16& oh = h ? o1 : o0;
#pragma unroll
    for (int rg = 0; rg < 4; rg++) {
      // d_local = 8*rg + 4*hi + g, n = c32
      *(float4*)&sc[c32 * 36 + 8 * rg + 4 * hi] =
          make_float4(oh[4 * rg + 0], oh[4 * rg + 1], oh[4 * rg + 2], oh[4 * rg + 3]);
    }
    // wave-private in-order LDS: read rows, coalesced atomics (2 n-rows x 32 d per instr)
#pragma unroll
    for (int rr = 0; rr < 16; rr++) {
      const int row = 2 * rr + hi;
      float v = sc[row * 36 + c32];
      atomicAdd(&nb[(size_t)row * Dd + h * 32 + c32], v);
    }
  }
  if (hi == 0)
    atomicAdd(&den_acc[(size_t)bb * N_ + n0 + w * 32 + c32], dacc);
}

__global__ __launch_bounds__(256) void msdiv_kernel(
    const float* __restrict__ num, const float* __restrict__ den,
    float* __restrict__ out) {
  const int i = blockIdx.x * 256 + threadIdx.x;  // float4 index; grid covers exactly
  float4 v = ((const float4*)num)[i];
  const float inv = 1.0f / den[i >> 4];          // 16 float4 per 64-wide row
  ((float4*)out)[i] = make_float4(v.x * inv, v.y * inv, v.z * inv, v.w * inv);
}

extern "C" void kernel_launch(void* const* d_in, const int* in_sizes, int n_in,
                              void* d_out, int out_size, void* d_ws, size_t ws_size,
                              hipStream_t stream) {
  const float* pts = (const float*)d_in[0];
  const float* ref = (const float*)d_in[1];
  float* out = (float*)d_out;
  float* num = (float*)d_ws;                       // [B,N,64] fp32 partial numerators
  float* den = num + (size_t)B_ * N_ * Dd;         // [B,N]    fp32 partial denominators
  const size_t acc_bytes = ((size_t)B_ * N_ * Dd + (size_t)B_ * N_) * sizeof(float);

  hipMemsetAsync(d_ws, 0, acc_bytes, stream);      // ws is re-poisoned 0xAA each launch
  msflash_kernel<<<dim3(B_ * NT * SPLIT), dim3(256), 0, stream>>>(pts, ref, num, den);
  const int tot4 = B_ * N_ * Dd / 4;               // 262144
  msdiv_kernel<<<dim3(tot4 / 256), dim3(256), 0, stream>>>(num, den, out);
}